// Round 4
// baseline (495.983 us; speedup 1.0000x reference)
//
#include <hip/hip_runtime.h>

// Problem constants
#define BB   8
#define CIN  256
#define COUT 256
#define HH   64
#define WW   64
#define HW   (HH*WW)        // 4096
#define KT   9
#define KTOT (CIN*KT)       // 2304
#define NSLAB 80            // 16 ch-groups x 5 tap-pairs (K padded to 2560)
#define WR   12             // staged window rows
#define WSTRIDE 772         // floats per ch slot (12*64 + 4 pad) = 3088 B

typedef short short8 __attribute__((ext_vector_type(8)));
typedef float f32x4  __attribute__((ext_vector_type(4)));
struct F2 { float x, y; };               // 4-byte aligned float pair (ds_read2)
union FragU { short8 s8; unsigned short us[8]; uint4 u4; };

// Workspace layout (float offsets)
#define WS_OFF     0            // [B][2][HW]
#define WS_SCALE   65536        // [B][HW]
#define WS_PART    98304        // 64 partial absmax of w_dcn
#define WS_WOFFQ   98368        // [2][CIN][9]
#define WS_WSCALEQ 102976       // [CIN][9]
#define WS_B       105296       // bf16[NSLAB*16*64*8] = 1.31 MB

__device__ __forceinline__ float fq(float w, float s) {
    float q = rintf(w / s);              // RNE, matches jnp.round
    q = fminf(fmaxf(q, -8.f), 7.f);
    return q * s;
}

__device__ __forceinline__ unsigned short f2bf(float f) {
    unsigned u = __float_as_uint(f);
    return (unsigned short)((u + 0x7fffu + ((u >> 16) & 1u)) >> 16);  // RNE
}

// =============== K1: absmax partials + small-tensor quant =====================
__global__ __launch_bounds__(256) void prep_kernel(const float* __restrict__ w_dcn,
                                                   const float* __restrict__ w_off,
                                                   const float* __restrict__ w_scale,
                                                   float* __restrict__ ws) {
    __shared__ float red[256];
    const int bx = blockIdx.x, tid = threadIdx.x;
    if (bx < 64) {                       // partial absmax of w_dcn
        float m = 0.f;
        const float* p = w_dcn + bx * 9216;
#pragma unroll
        for (int k = 0; k < 36; ++k) m = fmaxf(m, fabsf(p[tid + k * 256]));
        red[tid] = m;
        __syncthreads();
        for (int s = 128; s > 0; s >>= 1) {
            if (tid < s) red[tid] = fmaxf(red[tid], red[tid + s]);
            __syncthreads();
        }
        if (tid == 0) ws[WS_PART + bx] = red[0];
    } else {                             // small tensors: absmax + quantize
        const float* src = (bx == 64) ? w_off : w_scale;
        const int n = (bx == 64) ? 2 * KTOT : KTOT;
        float* dst = ws + ((bx == 64) ? WS_WOFFQ : WS_WSCALEQ);
        float m = 0.f;
        for (int i = tid; i < n; i += 256) m = fmaxf(m, fabsf(src[i]));
        red[tid] = m;
        __syncthreads();
        for (int s = 128; s > 0; s >>= 1) {
            if (tid < s) red[tid] = fmaxf(red[tid], red[tid + s]);
            __syncthreads();
        }
        float sq = fmaxf(red[0], 1e-8f) / 7.f;
        for (int i = tid; i < n; i += 256) dst[i] = fq(src[i], sq);
    }
}

// =============== K2: offset/scale conv + w_dcn quant to bf16 B-frags ==========
__global__ __launch_bounds__(256) void mid_kernel(const float* __restrict__ x,
                                                  const float* __restrict__ w_dcn,
                                                  float* __restrict__ ws) {
    __shared__ float R[4][3][64];
    const int bx = blockIdx.x, tid = threadIdx.x;
    if (bx < 512) {
        // ---- offset/scale 3x3 conv, one (b,i) row per block ----
        const int b = bx & 7, i = bx >> 3;
        const int j = tid & 63, cq = tid >> 6;
        const float* woq = ws + WS_WOFFQ;
        const float* wsq = ws + WS_WSCALEQ;
        float a0 = 0.f, a1 = 0.f, a2 = 0.f;
        for (int c = cq * 64; c < cq * 64 + 64; ++c) {
            const float* xb = x + (size_t)(b * CIN + c) * HW;
            const float* w0 = woq + c * 9;
            const float* w1 = woq + KTOT + c * 9;
            const float* w2 = wsq + c * 9;
#pragma unroll
            for (int di = -1; di <= 1; ++di) {
                int yy = i + di;
                bool rv = (yy >= 0) && (yy < HH);
#pragma unroll
                for (int dj = -1; dj <= 1; ++dj) {
                    int xx = j + dj;
                    float xv = (rv && xx >= 0 && xx < WW) ? xb[yy * WW + xx] : 0.f;
                    int t = (di + 1) * 3 + (dj + 1);
                    a0 += xv * w0[t];
                    a1 += xv * w1[t];
                    a2 += xv * w2[t];
                }
            }
        }
        R[cq][0][j] = a0; R[cq][1][j] = a1; R[cq][2][j] = a2;
        __syncthreads();
        if (tid < 192) {
            int comp = tid >> 6, j2 = tid & 63;
            float v = R[0][comp][j2] + R[1][comp][j2] +
                      R[2][comp][j2] + R[3][comp][j2];
            if (comp == 0)      ws[WS_OFF + (b * 2 + 0) * HW + i * WW + j2] = v;
            else if (comp == 1) ws[WS_OFF + (b * 2 + 1) * HW + i * WW + j2] = v;
            else                ws[WS_SCALE + b * HW + i * WW + j2] = v;
        }
    } else {
        // ---- quantize w_dcn -> bf16 MFMA B-fragment stream ----
        // entry t = ((s*16 + nt)*64 + l)*8 + j ; k = (l>>4)*8 + j ;
        // c = k>>1, tt = k&1, tap = p*2+tt (0 if tap==9), ch = g*16+c,
        // o = nt*16 + (l&15), with s = g*5 + p.
        const int qb = bx - 512;          // 0..639
        float m = 0.f;
#pragma unroll
        for (int k = 0; k < 64; ++k) m = fmaxf(m, ws[WS_PART + k]);
        float sd = fmaxf(m, 1e-8f) / 7.f;
        const int t4 = (qb * 256 + tid) * 4;
        unsigned short v4[4];
#pragma unroll
        for (int u = 0; u < 4; ++u) {
            int t = t4 + u;
            int j  = t & 7;
            int l  = (t >> 3) & 63;
            int nt = (t >> 9) & 15;
            int s  = t >> 13;
            int g = s / 5, p = s - g * 5;
            int k = ((l >> 4) << 3) + j;
            int c = k >> 1, tt = k & 1;
            int tap = p * 2 + tt;
            int ch = g * 16 + c;
            int o = nt * 16 + (l & 15);
            float v = (tap <= 8) ? fq(w_dcn[(o * CIN + ch) * KT + tap], sd) : 0.f;
            v4[u] = f2bf(v);
        }
        unsigned lo = (unsigned)v4[0] | ((unsigned)v4[1] << 16);
        unsigned hi = (unsigned)v4[2] | ((unsigned)v4[3] << 16);
        ((uint2*)((char*)(ws + WS_B)))[qb * 256 + tid] = make_uint2(lo, hi);
    }
}

// =============== K3: main fused deformable conv (MFMA bf16) ===================
// Block = (b, row-pair): M=128 px x N=256 outs, 512 thr / 8 waves, grid 256.
// Wave w = m-tile w (row i0+(w>>2), cols (w&3)*16..+16), all 16 n-tiles.
// K channel-major: 16 ch-groups x 5 tap-pairs (pad tap -> B=0). Per group,
// 12-row x 16-ch fp32 x-window staged densely in LDS; A-fragments built by
// per-lane bilinear gathers from LDS (ds crossbar, not global TA). Fallback
// to global gathers if block row-span > 12. Meta in registers.
__global__ __launch_bounds__(512, 2) void dcn_main_kernel(
    const float* __restrict__ x, const float* __restrict__ b_off,
    const float* __restrict__ b_scale, const float* __restrict__ b_dcn,
    const float* __restrict__ ws, float* __restrict__ out) {
    __shared__ float sWin[16 * WSTRIDE];   // 49408 B
    __shared__ int sRed[2];
    const int tid = threadIdx.x;
    const int bx = blockIdx.x;
    const int b = bx & 7;                  // XCD swizzle: batch -> XCD
    const int i0 = (bx >> 3) * 2;
    const int w = tid >> 6, l = tid & 63;
    const int q = l >> 4, ln = l & 15;
    const int row_i = i0 + (w >> 2);
    const int colp = ((w & 3) << 4) + ln;  // this lane's A-pixel column
    const float* xb = x + (size_t)b * CIN * HW;
    const char* Bw = (const char*)(ws + WS_B);

    if (tid == 0) { sRed[0] = 64; sRed[1] = -1; }

    // ---- phase 0: per-lane bilinear meta for 9 taps (registers) ----
    unsigned mRC[9], mW0[9], mW1[9];
    {
        float o0 = ws[WS_OFF + (b * 2 + 0) * HW + row_i * WW + colp] + b_off[0];
        float o1 = ws[WS_OFF + (b * 2 + 1) * HW + row_i * WW + colp] + b_off[1];
        float sc = fmaxf(ws[WS_SCALE + b * HW + row_i * WW + colp] + b_scale[0], 0.f);
        int rmn = 64, rmx = -1;
#pragma unroll
        for (int tap = 0; tap < 9; ++tap) {
            float ry = (float)(tap / 3 - 1), rx = (float)(tap % 3 - 1);
            float py = (float)row_i + ry * sc + o0;
            float px = (float)colp + rx * sc + o1;
            float y0f = floorf(py), x0f = floorf(px);
            float wy = py - y0f, wx = px - x0f;
            float w00 = (1.f - wy) * (1.f - wx), w01 = (1.f - wy) * wx;
            float w10 = wy * (1.f - wx),         w11 = wy * wx;
            bool vy0 = (y0f >= 0.f)  && (y0f <= 63.f);
            bool vy1 = (y0f >= -1.f) && (y0f <= 62.f);
            bool vx0 = (x0f >= 0.f)  && (x0f <= 63.f);
            bool vx1 = (x0f >= -1.f) && (x0f <= 62.f);
            bool d0hi = x0f > 62.f, d1lo = x0f < 0.f;
            float e0 = 0.f, e1 = 0.f, e2 = 0.f, e3 = 0.f;
            if (vy0 && vx0) { if (d0hi) e1 += w00; else e0 += w00; }
            if (vy0 && vx1) { if (d1lo) e0 += w01; else e1 += w01; }
            if (vy1 && vx0) { if (d0hi) e3 += w10; else e2 += w10; }
            if (vy1 && vx1) { if (d1lo) e2 += w11; else e3 += w11; }
            int r0 = (int)fminf(fmaxf(y0f, 0.f), 63.f);
            int r1 = (int)fminf(fmaxf(y0f + 1.f, 0.f), 63.f);
            int cb = (int)fminf(fmaxf(x0f, 0.f), 62.f);
            bool use0 = (e0 != 0.f) || (e1 != 0.f);
            bool use1 = (e2 != 0.f) || (e3 != 0.f);
            if (use0) { rmn = min(rmn, r0); rmx = max(rmx, r0); }
            if (use1) { rmn = min(rmn, r1); rmx = max(rmx, r1); }
            mRC[tap] = (unsigned)r0 | ((unsigned)r1 << 8) | ((unsigned)cb << 16) |
                       ((unsigned)use0 << 24) | ((unsigned)use1 << 25);
            mW0[tap] = (unsigned)f2bf(e0) | ((unsigned)f2bf(e1) << 16);
            mW1[tap] = (unsigned)f2bf(e2) | ((unsigned)f2bf(e3) << 16);
        }
        __syncthreads();                  // sRed init visible
        atomicMin(&sRed[0], rmn);
        atomicMax(&sRed[1], rmx);
    }
    __syncthreads();
    const int rmin = sRed[0], rmax = sRed[1];
    const int rlo = min(max(rmin, 0), HH - WR);
    const bool fast = (rmax - rlo) <= (WR - 1);

    unsigned mOb[9];
#pragma unroll
    for (int tap = 0; tap < 9; ++tap) {
        unsigned rc = mRC[tap];
        int r0 = rc & 0xff, r1 = (rc >> 8) & 0xff, cb = (rc >> 16) & 0xff;
        int u0 = (rc >> 24) & 1, u1 = (rc >> 25) & 1;
        int a0, a1;
        if (fast) {
            a0 = ((u0 ? (r0 - rlo) : 0) * WW + cb) * 4;
            a1 = ((u1 ? (r1 - rlo) : 0) * WW + cb) * 4;
        } else {
            a0 = (r0 * WW + cb) * 4;
            a1 = (r1 * WW + cb) * 4;
        }
        mOb[tap] = (unsigned)a0 | ((unsigned)a1 << 16);
    }

    f32x4 acc[16];
#pragma unroll
    for (int n = 0; n < 16; ++n) acc[n] = (f32x4){0.f, 0.f, 0.f, 0.f};

#define KBODY(FASTMODE)                                                        \
    for (int g = 0; g < 16; ++g) {                                             \
        if (FASTMODE) {                                                        \
            __syncthreads();                                                   \
            _Pragma("unroll")                                                  \
            for (int r = 0; r < 6; ++r) {                                      \
                int c = 2 * w + (r >= 3 ? 1 : 0);                              \
                int kb = (r >= 3) ? r - 3 : r;                                 \
                const float* src = xb + (size_t)(g * 16 + c) * HW +            \
                                   rlo * WW + kb * 256;                        \
                __builtin_amdgcn_global_load_lds(                              \
                    (const __attribute__((address_space(1))) void*)(src + l * 4), \
                    (__attribute__((address_space(3))) void*)                  \
                        ((char*)sWin + c * 3088 + kb * 1024),                  \
                    16, 0, 0);                                                 \
            }                                                                  \
            __syncthreads();                                                   \
        }                                                                      \
        _Pragma("unroll")                                                      \
        for (int p = 0; p < 5; ++p) {                                          \
            float av[8];                                                       \
            _Pragma("unroll")                                                  \
            for (int jc = 0; jc < 4; ++jc) {                                   \
                _Pragma("unroll")                                              \
                for (int t = 0; t < 2; ++t) {                                  \
                    const int tap = (2 * p + t > 8) ? 8 : (2 * p + t);         \
                    unsigned ob = mOb[tap];                                    \
                    float w00 = __uint_as_float(mW0[tap] << 16);               \
                    float w01 = __uint_as_float(mW0[tap] & 0xffff0000u);       \
                    float w10 = __uint_as_float(mW1[tap] << 16);               \
                    float w11 = __uint_as_float(mW1[tap] & 0xffff0000u);       \
                    float s0x, s0y, s1x, s1y;                                  \
                    if (FASTMODE) {                                            \
                        const char* base = (const char*)sWin +                 \
                                           (q * 4 + jc) * 3088;                \
                        F2 v0 = *(const F2*)(base + (ob & 0xffffu));           \
                        F2 v1 = *(const F2*)(base + (ob >> 16));               \
                        s0x = v0.x; s0y = v0.y; s1x = v1.x; s1y = v1.y;        \
                    } else {                                                   \
                        const char* pb = (const char*)(xb +                    \
                            (size_t)(g * 16 + q * 4 + jc) * HW);               \
                        s0x = *(const float*)(pb + (ob & 0xffffu));            \
                        s0y = *(const float*)(pb + (ob & 0xffffu) + 4);        \
                        s1x = *(const float*)(pb + (ob >> 16));                \
                        s1y = *(const float*)(pb + (ob >> 16) + 4);            \
                    }                                                          \
                    av[jc * 2 + t] = w00 * s0x + w01 * s0y +                   \
                                     w10 * s1x + w11 * s1y;                    \
                }                                                              \
            }                                                                  \
            FragU af;                                                          \
            _Pragma("unroll")                                                  \
            for (int j = 0; j < 8; ++j) af.us[j] = f2bf(av[j]);                \
            const int s = g * 5 + p;                                           \
            const uint4* bp = (const uint4*)(Bw +                              \
                ((size_t)s * 16 * 64 + l) * 16);                               \
            _Pragma("unroll")                                                  \
            for (int nt = 0; nt < 16; ++nt) {                                  \
                FragU bf;                                                      \
                bf.u4 = bp[nt * 64];                                           \
                acc[nt] = __builtin_amdgcn_mfma_f32_16x16x32_bf16(             \
                    af.s8, bf.s8, acc[nt], 0, 0, 0);                           \
            }                                                                  \
        }                                                                      \
    }

    if (fast) { KBODY(true) } else { KBODY(false) }
#undef KBODY

    // ---- epilogue: direct stores (4 lanes with same ln cover a 64B line) ----
    const int col0 = ((w & 3) << 4) + (q << 2);
#pragma unroll
    for (int nt = 0; nt < 16; ++nt) {
        int o = nt * 16 + ln;
        float bb = b_dcn[o];
        f32x4 v = acc[nt];
        v.x += bb; v.y += bb; v.z += bb; v.w += bb;
        *(f32x4*)(out + ((size_t)(b * COUT + o) * HH + row_i) * WW + col0) = v;
    }
}

extern "C" void kernel_launch(void* const* d_in, const int* in_sizes, int n_in,
                              void* d_out, int out_size, void* d_ws, size_t ws_size,
                              hipStream_t stream) {
    const float* x       = (const float*)d_in[0];
    const float* w_off   = (const float*)d_in[1];
    const float* b_off   = (const float*)d_in[2];
    const float* w_scale = (const float*)d_in[3];
    const float* b_scale = (const float*)d_in[4];
    const float* w_dcn   = (const float*)d_in[5];
    const float* b_dcn   = (const float*)d_in[6];
    float* out = (float*)d_out;
    float* ws  = (float*)d_ws;

    prep_kernel<<<dim3(66),   dim3(256), 0, stream>>>(w_dcn, w_off, w_scale, ws);
    mid_kernel <<<dim3(1152), dim3(256), 0, stream>>>(x, w_dcn, ws);
    dcn_main_kernel<<<dim3(256), dim3(512), 0, stream>>>(
        x, b_off, b_scale, b_dcn, ws, out);
}

// Round 5
// 309.788 us; speedup vs baseline: 1.6010x; 1.6010x over previous
//
#include <hip/hip_runtime.h>

// Problem constants
#define BB   8
#define CIN  256
#define COUT 256
#define HH   64
#define WW   64
#define HW   (HH*WW)        // 4096
#define KT   9
#define KTOT (CIN*KT)       // 2304
#define NSLAB 16            // channel groups of 16
#define WR   14             // staged window rows
#define RSTR 65             // dwords per window row  (bank +1 per row)
#define CSTR 914            // dwords per window ch   (914 % 8 == 2 -> q-groups at banks 0/8/16/24)

typedef short short8 __attribute__((ext_vector_type(8)));
typedef float f32x4  __attribute__((ext_vector_type(4)));
typedef float f32x2  __attribute__((ext_vector_type(2)));
union FragU { short8 s8; unsigned u[4]; uint4 u4; };

// Workspace layout (float offsets)
#define WS_OFF     0            // [B][2][HW]
#define WS_SCALE   65536        // [B][HW]
#define WS_PART    98304        // 64 partial absmax of w_dcn
#define WS_SDCN    98368        // s_dcn (+3 pad)
#define WS_WOFFQ   98372        // [2][CIN][9]
#define WS_WSCALEQ 102980       // [CIN][9]
#define WS_B       105284       // fp8-int bytes [80][8][64][16] = 655360 B (16B aligned)

#define USE_FP8_HW __has_builtin(__builtin_amdgcn_cvt_pk_f32_fp8)

__device__ __forceinline__ float fq(float w, float s) {
    float q = rintf(w / s);              // RNE, matches jnp.round
    q = fminf(fmaxf(q, -8.f), 7.f);
    return q * s;
}

__device__ __forceinline__ unsigned short f2bf(float f) {
    unsigned u = __float_as_uint(f);
    return (unsigned short)((u + 0x7fffu + ((u >> 16) & 1u)) >> 16);  // RNE
}

// =============== K1: absmax partials + small-tensor quant =====================
__global__ __launch_bounds__(256) void prep_kernel(const float* __restrict__ w_dcn,
                                                   const float* __restrict__ w_off,
                                                   const float* __restrict__ w_scale,
                                                   float* __restrict__ ws) {
    __shared__ float red[256];
    const int bx = blockIdx.x, tid = threadIdx.x;
    if (bx < 64) {                       // partial absmax of w_dcn
        float m = 0.f;
        const float* p = w_dcn + bx * 9216;
#pragma unroll
        for (int k = 0; k < 36; ++k) m = fmaxf(m, fabsf(p[tid + k * 256]));
        red[tid] = m;
        __syncthreads();
        for (int s = 128; s > 0; s >>= 1) {
            if (tid < s) red[tid] = fmaxf(red[tid], red[tid + s]);
            __syncthreads();
        }
        if (tid == 0) ws[WS_PART + bx] = red[0];
    } else {                             // small tensors: absmax + quantize
        const float* src = (bx == 64) ? w_off : w_scale;
        const int n = (bx == 64) ? 2 * KTOT : KTOT;
        float* dst = ws + ((bx == 64) ? WS_WOFFQ : WS_WSCALEQ);
        float m = 0.f;
        for (int i = tid; i < n; i += 256) m = fmaxf(m, fabsf(src[i]));
        red[tid] = m;
        __syncthreads();
        for (int s = 128; s > 0; s >>= 1) {
            if (tid < s) red[tid] = fmaxf(red[tid], red[tid + s]);
            __syncthreads();
        }
        float sq = fmaxf(red[0], 1e-8f) / 7.f;
        for (int i = tid; i < n; i += 256) dst[i] = fq(src[i], sq);
    }
}

// =============== K2: offset/scale conv + w_dcn quant to fp8-int B =============
// B layout: byte t = ((((s*8 + np)*64 + l)*16) + h*8 + j); s = g*5+p;
// nt = np*2+h; o = nt*16 + (l&15); k = (l>>4)*8 + j; ch = g*16 + (k>>1);
// tap = p*2 + (k&1) (tap 9 -> 0 pad).
__global__ __launch_bounds__(256) void mid_kernel(const float* __restrict__ x,
                                                  const float* __restrict__ w_dcn,
                                                  float* __restrict__ ws) {
    __shared__ float R[4][3][64];
    const int bx = blockIdx.x, tid = threadIdx.x;
    if (bx < 512) {
        // ---- offset/scale 3x3 conv, one (b,i) row per block ----
        const int b = bx & 7, i = bx >> 3;
        const int j = tid & 63, cq = tid >> 6;
        const float* woq = ws + WS_WOFFQ;
        const float* wsq = ws + WS_WSCALEQ;
        float a0 = 0.f, a1 = 0.f, a2 = 0.f;
        for (int c = cq * 64; c < cq * 64 + 64; ++c) {
            const float* xb = x + (size_t)(b * CIN + c) * HW;
            const float* w0 = woq + c * 9;
            const float* w1 = woq + KTOT + c * 9;
            const float* w2 = wsq + c * 9;
#pragma unroll
            for (int di = -1; di <= 1; ++di) {
                int yy = i + di;
                bool rv = (yy >= 0) && (yy < HH);
#pragma unroll
                for (int dj = -1; dj <= 1; ++dj) {
                    int xx = j + dj;
                    float xv = (rv && xx >= 0 && xx < WW) ? xb[yy * WW + xx] : 0.f;
                    int t = (di + 1) * 3 + (dj + 1);
                    a0 += xv * w0[t];
                    a1 += xv * w1[t];
                    a2 += xv * w2[t];
                }
            }
        }
        R[cq][0][j] = a0; R[cq][1][j] = a1; R[cq][2][j] = a2;
        __syncthreads();
        if (tid < 192) {
            int comp = tid >> 6, j2 = tid & 63;
            float v = R[0][comp][j2] + R[1][comp][j2] +
                      R[2][comp][j2] + R[3][comp][j2];
            if (comp == 0)      ws[WS_OFF + (b * 2 + 0) * HW + i * WW + j2] = v;
            else if (comp == 1) ws[WS_OFF + (b * 2 + 1) * HW + i * WW + j2] = v;
            else                ws[WS_SCALE + b * HW + i * WW + j2] = v;
        }
    } else {
        // ---- quantize w_dcn -> fp8-encoded raw ints ----
        const int qb = bx - 512;          // 0..639
        float m = 0.f;
#pragma unroll
        for (int k = 0; k < 64; ++k) m = fmaxf(m, ws[WS_PART + k]);
        float sd = fmaxf(m, 1e-8f) / 7.f;
        if (qb == 0 && tid == 0) ws[WS_SDCN] = sd;
        const int t4 = (qb * 256 + tid) * 4;
        float qv[4];
#pragma unroll
        for (int u = 0; u < 4; ++u) {
            int t = t4 + u;
            int j  = t & 7;
            int h  = (t >> 3) & 1;
            int l  = (t >> 4) & 63;
            int np = (t >> 10) & 7;
            int s  = t >> 13;             // 0..79
            int g = s / 5, p = s - g * 5;
            int k = ((l >> 4) << 3) + j;
            int ch = g * 16 + (k >> 1);
            int tap = p * 2 + (k & 1);
            int o = (np * 2 + h) * 16 + (l & 15);
            float w = (tap <= 8) ? w_dcn[(o * CIN + ch) * KT + tap] : 0.f;
            qv[u] = fminf(fmaxf(rintf(w / sd), -8.f), 7.f);
        }
        unsigned d;
#if USE_FP8_HW
        d = 0;
        d = __builtin_amdgcn_cvt_pk_fp8_f32(qv[0], qv[1], d, false);
        d = __builtin_amdgcn_cvt_pk_fp8_f32(qv[2], qv[3], d, true);
#else
        d = ((unsigned)(unsigned char)(signed char)(int)qv[0])
          | ((unsigned)(unsigned char)(signed char)(int)qv[1] << 8)
          | ((unsigned)(unsigned char)(signed char)(int)qv[2] << 16)
          | ((unsigned)(unsigned char)(signed char)(int)qv[3] << 24);
#endif
        ((unsigned*)(ws + WS_B))[qb * 256 + tid] = d;
    }
}

// fp8-int x4 -> two packed-bf16 dwords (1 VALU op per weight)
__device__ __forceinline__ void cvt4(unsigned d, unsigned& p0, unsigned& p1) {
#if USE_FP8_HW
    f32x2 lo = __builtin_amdgcn_cvt_pk_f32_fp8(d, false);
    f32x2 hi = __builtin_amdgcn_cvt_pk_f32_fp8(d, true);
    p0 = __builtin_amdgcn_perm(__float_as_uint(lo.y), __float_as_uint(lo.x),
                               0x07060302u);
    p1 = __builtin_amdgcn_perm(__float_as_uint(hi.y), __float_as_uint(hi.x),
                               0x07060302u);
#else
    float f0 = (float)(int)(signed char)(d & 0xff);
    float f1 = (float)(int)(signed char)((d >> 8) & 0xff);
    float f2 = (float)(int)(signed char)((d >> 16) & 0xff);
    float f3 = (float)(int)(signed char)(d >> 24);
    p0 = __builtin_amdgcn_perm(__float_as_uint(f1), __float_as_uint(f0),
                               0x07060302u);
    p1 = __builtin_amdgcn_perm(__float_as_uint(f3), __float_as_uint(f2),
                               0x07060302u);
#endif
}

// =============== K3: main fused deformable conv (MFMA bf16) ===================
// Block = (b, row-pair): M=128 px x N=256 outs, 512 thr / 8 waves, grid 256
// (exactly 1 block/CU). Wave w = m-tile w, all 16 n-tiles. K channel-major:
// 16 slabs of 16 ch x 5 tap-pairs. Per slab a WRx16-ch window of x is staged
// in LDS as pre-paired bf16 dwords (dword[c] = bf16(x[c])|bf16(x[c+1])<<16):
// one ds_read_b32 per bilinear row. Double-buffered window; barrier-free
// K-body, 1 barrier/slab. B = fp8 raw ints direct global->reg (s_dcn folded
// into A bilinear weights). Fallback to global gathers if row-span > WR.
__global__ __launch_bounds__(512, 2) void dcn_main_kernel(
    const float* __restrict__ x, const float* __restrict__ b_off,
    const float* __restrict__ b_scale, const float* __restrict__ b_dcn,
    const float* __restrict__ ws, float* __restrict__ out) {
    __shared__ unsigned sWin[2][16 * CSTR];     // 2 x 58496 B
    __shared__ int sRed[2];
    const int tid = threadIdx.x;
    const int bx = blockIdx.x;
    const int b = bx & 7;                  // XCD swizzle: batch -> XCD
    const int i0 = (bx >> 3) * 2;
    const int w = tid >> 6, l = tid & 63;
    const int q = l >> 4, ln = l & 15;
    const int row_i = i0 + (w >> 2);
    const int colp = ((w & 3) << 4) + ln;  // this lane's A-pixel column
    const float* xb = x + (size_t)b * CIN * HW;
    const char* Bb = (const char*)(ws + WS_B);
    const float sdcn = ws[WS_SDCN];

    if (tid == 0) { sRed[0] = 64; sRed[1] = -1; }

    // ---- phase 0: per-lane bilinear meta for 9 taps (registers) ----
    unsigned mRC[9], mW0[9], mW1[9];
    {
        float o0 = ws[WS_OFF + (b * 2 + 0) * HW + row_i * WW + colp] + b_off[0];
        float o1 = ws[WS_OFF + (b * 2 + 1) * HW + row_i * WW + colp] + b_off[1];
        float sc = fmaxf(ws[WS_SCALE + b * HW + row_i * WW + colp] + b_scale[0], 0.f);
        int rmn = 64, rmx = -1;
#pragma unroll
        for (int tap = 0; tap < 9; ++tap) {
            float ry = (float)(tap / 3 - 1), rx = (float)(tap % 3 - 1);
            float py = (float)row_i + ry * sc + o0;
            float px = (float)colp + rx * sc + o1;
            float y0f = floorf(py), x0f = floorf(px);
            float wy = py - y0f, wx = px - x0f;
            float w00 = (1.f - wy) * (1.f - wx), w01 = (1.f - wy) * wx;
            float w10 = wy * (1.f - wx),         w11 = wy * wx;
            bool vy0 = (y0f >= 0.f)  && (y0f <= 63.f);
            bool vy1 = (y0f >= -1.f) && (y0f <= 62.f);
            bool vx0 = (x0f >= 0.f)  && (x0f <= 63.f);
            bool vx1 = (x0f >= -1.f) && (x0f <= 62.f);
            bool d0hi = x0f > 62.f, d1lo = x0f < 0.f;
            float e0 = 0.f, e1 = 0.f, e2 = 0.f, e3 = 0.f;
            if (vy0 && vx0) { if (d0hi) e1 += w00; else e0 += w00; }
            if (vy0 && vx1) { if (d1lo) e0 += w01; else e1 += w01; }
            if (vy1 && vx0) { if (d0hi) e3 += w10; else e2 += w10; }
            if (vy1 && vx1) { if (d1lo) e2 += w11; else e3 += w11; }
            int r0 = (int)fminf(fmaxf(y0f, 0.f), 63.f);
            int r1 = (int)fminf(fmaxf(y0f + 1.f, 0.f), 63.f);
            int cb = (int)fminf(fmaxf(x0f, 0.f), 62.f);
            bool use0 = (e0 != 0.f) || (e1 != 0.f);
            bool use1 = (e2 != 0.f) || (e3 != 0.f);
            if (use0) { rmn = min(rmn, r0); rmx = max(rmx, r0); }
            if (use1) { rmn = min(rmn, r1); rmx = max(rmx, r1); }
            mRC[tap] = (unsigned)r0 | ((unsigned)r1 << 8) | ((unsigned)cb << 16) |
                       ((unsigned)use0 << 24) | ((unsigned)use1 << 25);
            mW0[tap] = (unsigned)f2bf(e0 * sdcn) | ((unsigned)f2bf(e1 * sdcn) << 16);
            mW1[tap] = (unsigned)f2bf(e2 * sdcn) | ((unsigned)f2bf(e3 * sdcn) << 16);
        }
        __syncthreads();                  // sRed init visible
        atomicMin(&sRed[0], rmn);
        atomicMax(&sRed[1], rmx);
    }
    __syncthreads();
    const int rmin = sRed[0], rmax = sRed[1];
    const int rlo = min(max(rmin, 0), HH - WR);
    const bool fast = (rmax - rlo) <= (WR - 1);

    unsigned mOb[9];
#pragma unroll
    for (int tap = 0; tap < 9; ++tap) {
        unsigned rc = mRC[tap];
        int r0 = rc & 0xff, r1 = (rc >> 8) & 0xff, cb = (rc >> 16) & 0xff;
        int u0 = (rc >> 24) & 1, u1 = (rc >> 25) & 1;
        int a0, a1;
        if (fast) {
            a0 = ((u0 ? (r0 - rlo) : 0) * RSTR + cb) * 4;   // bytes in window ch-slot
            a1 = ((u1 ? (r1 - rlo) : 0) * RSTR + cb) * 4;
        } else {
            a0 = (r0 * WW + cb) * 4;                         // bytes in x plane
            a1 = (r1 * WW + cb) * 4;
        }
        mOb[tap] = (unsigned)a0 | ((unsigned)a1 << 16);
    }

    f32x4 acc[16];
#pragma unroll
    for (int n = 0; n < 16; ++n) acc[n] = (f32x4){0.f, 0.f, 0.f, 0.f};

    const char* winB = (const char*)&sWin[0][0] + q * 4 * (CSTR * 4);

    // staging helpers: 7 groups of 4 dwords per thread per slab
    float4 stA[7]; float stB[7];
    auto stageLoad = [&](int g) {
#pragma unroll
        for (int sg = 0; sg < 7; ++sg) {
            int id = tid + sg * 512;
            int c4 = id & 15, rc = id >> 4;
            int ch = rc / WR, rr = rc - ch * WR;
            const float* src = xb + (size_t)(g * 16 + ch) * HW +
                               (rlo + rr) * WW + c4 * 4;
            stA[sg] = *(const float4*)src;
            stB[sg] = (c4 == 15) ? stA[sg].w : src[4];
        }
    };
    auto stageWrite = [&](int buf) {
#pragma unroll
        for (int sg = 0; sg < 7; ++sg) {
            int id = tid + sg * 512;
            int c4 = id & 15, rc = id >> 4;
            int ch = rc / WR, rr = rc - ch * WR;
            unsigned* wp = &sWin[buf][ch * CSTR + rr * RSTR + c4 * 4];
            float4 a = stA[sg]; float b5 = stB[sg];
            wp[0] = (unsigned)f2bf(a.x) | ((unsigned)f2bf(a.y) << 16);
            wp[1] = (unsigned)f2bf(a.y) | ((unsigned)f2bf(a.z) << 16);
            wp[2] = (unsigned)f2bf(a.z) | ((unsigned)f2bf(a.w) << 16);
            wp[3] = (unsigned)f2bf(a.w) | ((unsigned)f2bf(b5) << 16);
        }
    };

#define DECMFMA(RB, NP)                                                        \
    {                                                                          \
        FragU b0, b1;                                                          \
        cvt4(RB.x, b0.u[0], b0.u[1]); cvt4(RB.y, b0.u[2], b0.u[3]);            \
        cvt4(RB.z, b1.u[0], b1.u[1]); cvt4(RB.w, b1.u[2], b1.u[3]);            \
        acc[NP * 2 + 0] = __builtin_amdgcn_mfma_f32_16x16x32_bf16(             \
            af.s8, b0.s8, acc[NP * 2 + 0], 0, 0, 0);                           \
        acc[NP * 2 + 1] = __builtin_amdgcn_mfma_f32_16x16x32_bf16(             \
            af.s8, b1.s8, acc[NP * 2 + 1], 0, 0, 0);                           \
    }

#define KBODY(FASTMODE)                                                        \
    for (int g = 0; g < 16; ++g) {                                             \
        const int buf = g & 1;                                                 \
        if (FASTMODE && g < 15) stageLoad(g + 1);                              \
        _Pragma("unroll")                                                      \
        for (int p = 0; p < 5; ++p) {                                          \
            const int s = g * 5 + p;                                           \
            const char* bp = Bb + (size_t)s * 8192 + l * 16;                   \
            uint4 rb0 = *(const uint4*)(bp);                                   \
            uint4 rb1 = *(const uint4*)(bp + 1024);                            \
            uint4 rb2 = *(const uint4*)(bp + 2048);                            \
            uint4 rb3 = *(const uint4*)(bp + 3072);                            \
            uint4 rb4 = *(const uint4*)(bp + 4096);                            \
            uint4 rb5 = *(const uint4*)(bp + 5120);                            \
            uint4 rb6 = *(const uint4*)(bp + 6144);                            \
            uint4 rb7 = *(const uint4*)(bp + 7168);                            \
            FragU af;                                                          \
            _Pragma("unroll")                                                  \
            for (int jc = 0; jc < 4; ++jc) {                                   \
                float av0 = 0.f, av1 = 0.f;                                    \
                _Pragma("unroll")                                              \
                for (int t = 0; t < 2; ++t) {                                  \
                    const int tap = (2 * p + t > 8) ? 8 : (2 * p + t);         \
                    unsigned ob = mOb[tap];                                    \
                    float w00 = __uint_as_float(mW0[tap] << 16);               \
                    float w01 = __uint_as_float(mW0[tap] & 0xffff0000u);       \
                    float w10 = __uint_as_float(mW1[tap] << 16);               \
                    float w11 = __uint_as_float(mW1[tap] & 0xffff0000u);       \
                    float v;                                                   \
                    if (FASTMODE) {                                            \
                        const char* base = winB + buf * 58496 + jc * (CSTR * 4); \
                        unsigned dw0 = *(const unsigned*)(base + (ob & 0xffffu)); \
                        unsigned dw1 = *(const unsigned*)(base + (ob >> 16));  \
                        v = w00 * __uint_as_float(dw0 << 16) +                 \
                            w01 * __uint_as_float(dw0 & 0xffff0000u) +         \
                            w10 * __uint_as_float(dw1 << 16) +                 \
                            w11 * __uint_as_float(dw1 & 0xffff0000u);          \
                    } else {                                                   \
                        const char* pb = (const char*)(xb +                    \
                            (size_t)(g * 16 + q * 4 + jc) * HW);               \
                        float s0x = *(const float*)(pb + (ob & 0xffffu));      \
                        float s0y = *(const float*)(pb + (ob & 0xffffu) + 4);  \
                        float s1x = *(const float*)(pb + (ob >> 16));          \
                        float s1y = *(const float*)(pb + (ob >> 16) + 4);      \
                        v = w00 * s0x + w01 * s0y + w10 * s1x + w11 * s1y;     \
                    }                                                          \
                    if (t == 0) av0 = v; else av1 = v;                         \
                }                                                              \
                af.u[jc] = (unsigned)f2bf(av0) | ((unsigned)f2bf(av1) << 16);  \
            }                                                                  \
            DECMFMA(rb0, 0) DECMFMA(rb1, 1) DECMFMA(rb2, 2) DECMFMA(rb3, 3)    \
            DECMFMA(rb4, 4) DECMFMA(rb5, 5) DECMFMA(rb6, 6) DECMFMA(rb7, 7)    \
        }                                                                      \
        if (FASTMODE) {                                                        \
            if (g < 15) stageWrite(buf ^ 1);                                   \
            __syncthreads();                                                   \
        }                                                                      \
    }

    if (fast) {
        stageLoad(0);
        stageWrite(0);
        __syncthreads();
        KBODY(true)
    } else {
        KBODY(false)
    }
#undef KBODY
#undef DECMFMA

    // ---- epilogue: direct stores (4 lanes with same ln cover a 64B line) ----
    const int col0 = ((w & 3) << 4) + (q << 2);
#pragma unroll
    for (int nt = 0; nt < 16; ++nt) {
        int o = nt * 16 + ln;
        float bb = b_dcn[o];
        f32x4 v = acc[nt];
        v.x += bb; v.y += bb; v.z += bb; v.w += bb;
        *(f32x4*)(out + ((size_t)(b * COUT + o) * HH + row_i) * WW + col0) = v;
    }
}

extern "C" void kernel_launch(void* const* d_in, const int* in_sizes, int n_in,
                              void* d_out, int out_size, void* d_ws, size_t ws_size,
                              hipStream_t stream) {
    const float* x       = (const float*)d_in[0];
    const float* w_off   = (const float*)d_in[1];
    const float* b_off   = (const float*)d_in[2];
    const float* w_scale = (const float*)d_in[3];
    const float* b_scale = (const float*)d_in[4];
    const float* w_dcn   = (const float*)d_in[5];
    const float* b_dcn   = (const float*)d_in[6];
    float* out = (float*)d_out;
    float* ws  = (float*)d_ws;

    prep_kernel<<<dim3(66),   dim3(256), 0, stream>>>(w_dcn, w_off, w_scale, ws);
    mid_kernel <<<dim3(1152), dim3(256), 0, stream>>>(x, w_dcn, ws);
    dcn_main_kernel<<<dim3(256), dim3(512), 0, stream>>>(
        x, b_off, b_scale, b_dcn, ws, out);
}

// Round 6
// 285.655 us; speedup vs baseline: 1.7363x; 1.0845x over previous
//
#include <hip/hip_runtime.h>

// Problem constants
#define BB   8
#define CIN  256
#define COUT 256
#define HH   64
#define WW   64
#define HW   (HH*WW)        // 4096
#define KT   9
#define KTOT (CIN*KT)       // 2304
#define WR   12             // staged window rows
#define RSTR 65             // dwords per window row
#define CSTR 786            // dwords per window ch slot (786%8==2 -> half-groups split banks)

typedef short short8 __attribute__((ext_vector_type(8)));
typedef float f32x4  __attribute__((ext_vector_type(4)));
typedef float f32x2  __attribute__((ext_vector_type(2)));
typedef float f32x16 __attribute__((ext_vector_type(16)));
union FragU { short8 s8; unsigned u[4]; uint4 u4; };

// Workspace layout (float offsets)
#define WS_OFF     0            // [B][2][HW]
#define WS_SCALE   65536        // [B][HW]
#define WS_PART    98304        // 64 partial absmax of w_dcn
#define WS_SDCN    98368        // s_dcn (+3 pad)
#define WS_WOFFQ   98372        // [2][CIN][9]
#define WS_WSCALEQ 102980       // [CIN][9]
#define WS_B       105284       // fp8-int bytes [160][8][64][8] = 655360 B

#define USE_FP8_HW __has_builtin(__builtin_amdgcn_cvt_pk_f32_fp8)

__device__ __forceinline__ float fq(float w, float s) {
    float q = rintf(w / s);              // RNE, matches jnp.round
    q = fminf(fmaxf(q, -8.f), 7.f);
    return q * s;
}

__device__ __forceinline__ unsigned short f2bf(float f) {
    unsigned u = __float_as_uint(f);
    return (unsigned short)((u + 0x7fffu + ((u >> 16) & 1u)) >> 16);  // RNE
}

// =============== K1: absmax partials + small-tensor quant =====================
__global__ __launch_bounds__(256) void prep_kernel(const float* __restrict__ w_dcn,
                                                   const float* __restrict__ w_off,
                                                   const float* __restrict__ w_scale,
                                                   float* __restrict__ ws) {
    __shared__ float red[256];
    const int bx = blockIdx.x, tid = threadIdx.x;
    if (bx < 64) {                       // partial absmax of w_dcn
        float m = 0.f;
        const float* p = w_dcn + bx * 9216;
#pragma unroll
        for (int k = 0; k < 36; ++k) m = fmaxf(m, fabsf(p[tid + k * 256]));
        red[tid] = m;
        __syncthreads();
        for (int s = 128; s > 0; s >>= 1) {
            if (tid < s) red[tid] = fmaxf(red[tid], red[tid + s]);
            __syncthreads();
        }
        if (tid == 0) ws[WS_PART + bx] = red[0];
    } else {                             // small tensors: absmax + quantize
        const float* src = (bx == 64) ? w_off : w_scale;
        const int n = (bx == 64) ? 2 * KTOT : KTOT;
        float* dst = ws + ((bx == 64) ? WS_WOFFQ : WS_WSCALEQ);
        float m = 0.f;
        for (int i = tid; i < n; i += 256) m = fmaxf(m, fabsf(src[i]));
        red[tid] = m;
        __syncthreads();
        for (int s = 128; s > 0; s >>= 1) {
            if (tid < s) red[tid] = fmaxf(red[tid], red[tid + s]);
            __syncthreads();
        }
        float sq = fmaxf(red[0], 1e-8f) / 7.f;
        for (int i = tid; i < n; i += 256) dst[i] = fq(src[i], sq);
    }
}

// =============== K2: offset/scale conv + w_dcn quant to fp8-int B =============
// B byte t = ((s*8 + nt)*64 + l)*8 + j ; s = g*10 + p*2 + o8 (0..159);
// n = nt*32 + (l&31); ch = g*16 + o8*8 + (l>>5)*4 + (j>>1); tap = 2p + (j&1).
__global__ __launch_bounds__(256) void mid_kernel(const float* __restrict__ x,
                                                  const float* __restrict__ w_dcn,
                                                  float* __restrict__ ws) {
    __shared__ float R[4][3][64];
    const int bx = blockIdx.x, tid = threadIdx.x;
    if (bx < 512) {
        // ---- offset/scale 3x3 conv, one (b,i) row per block ----
        const int b = bx & 7, i = bx >> 3;
        const int j = tid & 63, cq = tid >> 6;
        const float* woq = ws + WS_WOFFQ;
        const float* wsq = ws + WS_WSCALEQ;
        float a0 = 0.f, a1 = 0.f, a2 = 0.f;
        for (int c = cq * 64; c < cq * 64 + 64; ++c) {
            const float* xb = x + (size_t)(b * CIN + c) * HW;
            const float* w0 = woq + c * 9;
            const float* w1 = woq + KTOT + c * 9;
            const float* w2 = wsq + c * 9;
#pragma unroll
            for (int di = -1; di <= 1; ++di) {
                int yy = i + di;
                bool rv = (yy >= 0) && (yy < HH);
#pragma unroll
                for (int dj = -1; dj <= 1; ++dj) {
                    int xx = j + dj;
                    float xv = (rv && xx >= 0 && xx < WW) ? xb[yy * WW + xx] : 0.f;
                    int t = (di + 1) * 3 + (dj + 1);
                    a0 += xv * w0[t];
                    a1 += xv * w1[t];
                    a2 += xv * w2[t];
                }
            }
        }
        R[cq][0][j] = a0; R[cq][1][j] = a1; R[cq][2][j] = a2;
        __syncthreads();
        if (tid < 192) {
            int comp = tid >> 6, j2 = tid & 63;
            float v = R[0][comp][j2] + R[1][comp][j2] +
                      R[2][comp][j2] + R[3][comp][j2];
            if (comp == 0)      ws[WS_OFF + (b * 2 + 0) * HW + i * WW + j2] = v;
            else if (comp == 1) ws[WS_OFF + (b * 2 + 1) * HW + i * WW + j2] = v;
            else                ws[WS_SCALE + b * HW + i * WW + j2] = v;
        }
    } else {
        // ---- quantize w_dcn -> fp8-encoded raw ints (32x32 frag layout) ----
        const int qb = bx - 512;          // 0..639
        float m = 0.f;
#pragma unroll
        for (int k = 0; k < 64; ++k) m = fmaxf(m, ws[WS_PART + k]);
        float sd = fmaxf(m, 1e-8f) / 7.f;
        if (qb == 0 && tid == 0) ws[WS_SDCN] = sd;
        const int t4 = (qb * 256 + tid) * 4;
        float qv[4];
#pragma unroll
        for (int u = 0; u < 4; ++u) {
            int t = t4 + u;
            int j  = t & 7;
            int l  = (t >> 3) & 63;
            int nt = (t >> 9) & 7;
            int s  = t >> 12;             // 0..159
            int g = s / 10, r = s - g * 10;
            int p = r >> 1, o8 = r & 1;
            int ch = g * 16 + o8 * 8 + ((l >> 5) << 2) + (j >> 1);
            int tap = 2 * p + (j & 1);
            int o = nt * 32 + (l & 31);
            float w = (tap <= 8) ? w_dcn[(o * CIN + ch) * KT + tap] : 0.f;
            qv[u] = fminf(fmaxf(rintf(w / sd), -8.f), 7.f);
        }
        unsigned d;
#if USE_FP8_HW
        d = 0;
        d = __builtin_amdgcn_cvt_pk_fp8_f32(qv[0], qv[1], d, false);
        d = __builtin_amdgcn_cvt_pk_fp8_f32(qv[2], qv[3], d, true);
#else
        d = ((unsigned)(unsigned char)(signed char)(int)qv[0])
          | ((unsigned)(unsigned char)(signed char)(int)qv[1] << 8)
          | ((unsigned)(unsigned char)(signed char)(int)qv[2] << 16)
          | ((unsigned)(unsigned char)(signed char)(int)qv[3] << 24);
#endif
        ((unsigned*)(ws + WS_B))[qb * 256 + tid] = d;
    }
}

// fp8-int x4 -> two packed-bf16 dwords (exact for small ints)
__device__ __forceinline__ void cvt4(unsigned d, unsigned& p0, unsigned& p1) {
#if USE_FP8_HW
    f32x2 lo = __builtin_amdgcn_cvt_pk_f32_fp8(d, false);
    f32x2 hi = __builtin_amdgcn_cvt_pk_f32_fp8(d, true);
    p0 = __builtin_amdgcn_perm(__float_as_uint(lo.y), __float_as_uint(lo.x),
                               0x07060302u);
    p1 = __builtin_amdgcn_perm(__float_as_uint(hi.y), __float_as_uint(hi.x),
                               0x07060302u);
#else
    float f0 = (float)(int)(signed char)(d & 0xff);
    float f1 = (float)(int)(signed char)((d >> 8) & 0xff);
    float f2 = (float)(int)(signed char)((d >> 16) & 0xff);
    float f3 = (float)(int)(signed char)(d >> 24);
    p0 = __builtin_amdgcn_perm(__float_as_uint(f1), __float_as_uint(f0),
                               0x07060302u);
    p1 = __builtin_amdgcn_perm(__float_as_uint(f3), __float_as_uint(f2),
                               0x07060302u);
#endif
}

// =============== K3: main fused deformable conv (MFMA bf16 32x32x16) ==========
// Grid 512 (2 blocks/CU), block (b,i): M=64 px (2 m-tiles of 32) x N=256
// (8 n-tiles of 32). 512 thr / 8 waves. Produce phase: waves build bilinear
// A-frags from LDS window into sA (each frag built ONCE); consume: wave
// (mtc=w&1, ntp=w>>1) reads A b128 + 2 fp8 B-frags, 2 MFMA/K-step. Window:
// 16 ch x WR rows, paired-bf16 dwords, single buffer; stage interleaved with
// consume. Fallback to global gathers if row-span > WR.
__global__ __launch_bounds__(512, 4) void dcn_main_kernel(
    const float* __restrict__ x, const float* __restrict__ b_off,
    const float* __restrict__ b_scale, const float* __restrict__ b_dcn,
    const float* __restrict__ ws, float* __restrict__ out) {
    __shared__ unsigned sWin[16 * CSTR];        // 50304 B
    __shared__ short8 sA[10][2][64];            // 20480 B
    __shared__ int sRed[2];
    const int tid = threadIdx.x;
    const int bx = blockIdx.x;
    const int b = bx & 7;                  // XCD swizzle: batch -> XCD
    const int i = bx >> 3;
    const int w = tid >> 6, l = tid & 63;
    const int h = l >> 5;
    const int mtp = w & 1;                 // produce m-tile
    const int colp = mtp * 32 + (l & 31);  // produce/meta pixel
    const int mtc = w & 1, ntp = w >> 1;   // consume roles
    const float* xb = x + (size_t)b * CIN * HW;
    const char* Bb = (const char*)(ws + WS_B);
    const float sdcn = ws[WS_SDCN];

    if (tid == 0) { sRed[0] = 64; sRed[1] = -1; }

    // ---- phase 0: per-lane bilinear meta for 9 taps (registers) ----
    unsigned mRC[9], mW0[9], mW1[9];
    {
        float o0 = ws[WS_OFF + (b * 2 + 0) * HW + i * WW + colp] + b_off[0];
        float o1 = ws[WS_OFF + (b * 2 + 1) * HW + i * WW + colp] + b_off[1];
        float sc = fmaxf(ws[WS_SCALE + b * HW + i * WW + colp] + b_scale[0], 0.f);
        int rmn = 64, rmx = -1;
#pragma unroll
        for (int tap = 0; tap < 9; ++tap) {
            float ry = (float)(tap / 3 - 1), rx = (float)(tap % 3 - 1);
            float py = (float)i + ry * sc + o0;
            float px = (float)colp + rx * sc + o1;
            float y0f = floorf(py), x0f = floorf(px);
            float wy = py - y0f, wx = px - x0f;
            float w00 = (1.f - wy) * (1.f - wx), w01 = (1.f - wy) * wx;
            float w10 = wy * (1.f - wx),         w11 = wy * wx;
            bool vy0 = (y0f >= 0.f)  && (y0f <= 63.f);
            bool vy1 = (y0f >= -1.f) && (y0f <= 62.f);
            bool vx0 = (x0f >= 0.f)  && (x0f <= 63.f);
            bool vx1 = (x0f >= -1.f) && (x0f <= 62.f);
            bool d0hi = x0f > 62.f, d1lo = x0f < 0.f;
            float e0 = 0.f, e1 = 0.f, e2 = 0.f, e3 = 0.f;
            if (vy0 && vx0) { if (d0hi) e1 += w00; else e0 += w00; }
            if (vy0 && vx1) { if (d1lo) e0 += w01; else e1 += w01; }
            if (vy1 && vx0) { if (d0hi) e3 += w10; else e2 += w10; }
            if (vy1 && vx1) { if (d1lo) e2 += w11; else e3 += w11; }
            int r0 = (int)fminf(fmaxf(y0f, 0.f), 63.f);
            int r1 = (int)fminf(fmaxf(y0f + 1.f, 0.f), 63.f);
            int cb = (int)fminf(fmaxf(x0f, 0.f), 62.f);
            bool use0 = (e0 != 0.f) || (e1 != 0.f);
            bool use1 = (e2 != 0.f) || (e3 != 0.f);
            if (use0) { rmn = min(rmn, r0); rmx = max(rmx, r0); }
            if (use1) { rmn = min(rmn, r1); rmx = max(rmx, r1); }
            mRC[tap] = (unsigned)r0 | ((unsigned)r1 << 8) | ((unsigned)cb << 16) |
                       ((unsigned)use0 << 24) | ((unsigned)use1 << 25);
            mW0[tap] = (unsigned)f2bf(e0 * sdcn) | ((unsigned)f2bf(e1 * sdcn) << 16);
            mW1[tap] = (unsigned)f2bf(e2 * sdcn) | ((unsigned)f2bf(e3 * sdcn) << 16);
        }
        __syncthreads();                  // sRed init visible
        atomicMin(&sRed[0], rmn);
        atomicMax(&sRed[1], rmx);
    }
    __syncthreads();
    const int rmin = sRed[0], rmax = sRed[1];
    const int rlo = min(max(rmin, 0), HH - WR);
    const bool fast = (rmax - rlo) <= (WR - 1);

    unsigned mOb[9];
#pragma unroll
    for (int tap = 0; tap < 9; ++tap) {
        unsigned rc = mRC[tap];
        int r0 = rc & 0xff, r1 = (rc >> 8) & 0xff, cb = (rc >> 16) & 0xff;
        int u0 = (rc >> 24) & 1, u1 = (rc >> 25) & 1;
        int a0, a1;
        if (fast) {
            a0 = ((u0 ? (r0 - rlo) : 0) * RSTR + cb) * 4;   // bytes in ch slot
            a1 = ((u1 ? (r1 - rlo) : 0) * RSTR + cb) * 4;
        } else {
            a0 = (r0 * WW + cb) * 4;                         // bytes in x plane
            a1 = (r1 * WW + cb) * 4;
        }
        mOb[tap] = (unsigned)a0 | ((unsigned)a1 << 16);
    }

    f32x16 acc0 = {0.f}, acc1 = {0.f};
#pragma unroll
    for (int r = 0; r < 16; ++r) { acc0[r] = 0.f; acc1[r] = 0.f; }

    // ---- produce one A-frag unit (ksl in [0,10), this wave's mtp) ----
    auto produceUnit = [&](int g, int ksl, bool fastm) {
        const int p = ksl >> 1, o8 = ksl & 1;
        FragU af;
#pragma unroll
        for (int jc = 0; jc < 4; ++jc) {
            float vv0 = 0.f, vv1 = 0.f;
            const int chs = o8 * 8 + h * 4 + jc;
#pragma unroll
            for (int t = 0; t < 2; ++t) {
                int tap = 2 * p + t; if (tap > 8) tap = 8;
                unsigned ob = mOb[tap];
                float w00 = __uint_as_float(mW0[tap] << 16);
                float w01 = __uint_as_float(mW0[tap] & 0xffff0000u);
                float w10 = __uint_as_float(mW1[tap] << 16);
                float w11 = __uint_as_float(mW1[tap] & 0xffff0000u);
                float v;
                if (fastm) {
                    const char* base = (const char*)sWin + chs * (CSTR * 4);
                    unsigned dw0 = *(const unsigned*)(base + (ob & 0xffffu));
                    unsigned dw1 = *(const unsigned*)(base + (ob >> 16));
                    v = w00 * __uint_as_float(dw0 << 16) +
                        w01 * __uint_as_float(dw0 & 0xffff0000u) +
                        w10 * __uint_as_float(dw1 << 16) +
                        w11 * __uint_as_float(dw1 & 0xffff0000u);
                } else {
                    const char* pb = (const char*)(xb + (size_t)(g * 16 + chs) * HW);
                    float s0x = *(const float*)(pb + (ob & 0xffffu));
                    float s0y = *(const float*)(pb + (ob & 0xffffu) + 4);
                    float s1x = *(const float*)(pb + (ob >> 16));
                    float s1y = *(const float*)(pb + (ob >> 16) + 4);
                    v = w00 * s0x + w01 * s0y + w10 * s1x + w11 * s1y;
                }
                if (t == 0) vv0 = v; else vv1 = v;
            }
            af.u[jc] = (unsigned)f2bf(vv0) | ((unsigned)f2bf(vv1) << 16);
        }
        sA[ksl][mtp][l] = af.s8;
    };
    auto produceAll = [&](int g, bool fastm) {
        produceUnit(g, w >> 1, fastm);
        produceUnit(g, (w + 8) >> 1, fastm);
        if (w < 4) produceUnit(g, (w + 16) >> 1, fastm);
    };

    // ---- consume one K-step ----
    auto consumeStep = [&](int g, int ks) {
        const int s = g * 10 + ks;
        short8 af = sA[ks][mtc][l];
        const char* bp = Bb + ((size_t)(s * 8 + ntp * 2) * 64 + l) * 8;
        uint2 r0 = *(const uint2*)bp;
        uint2 r1 = *(const uint2*)(bp + 512);
        FragU b0, b1;
        cvt4(r0.x, b0.u[0], b0.u[1]); cvt4(r0.y, b0.u[2], b0.u[3]);
        cvt4(r1.x, b1.u[0], b1.u[1]); cvt4(r1.y, b1.u[2], b1.u[3]);
        acc0 = __builtin_amdgcn_mfma_f32_32x32x16_bf16(af, b0.s8, acc0, 0, 0, 0);
        acc1 = __builtin_amdgcn_mfma_f32_32x32x16_bf16(af, b1.s8, acc1, 0, 0, 0);
    };

    // ---- window staging (6 chunks of 512 quads) ----
    const int c4 = tid & 15;
    float4 sa[3]; float sb[3];
    auto stageLoad3 = [&](int g, int c0) {
#pragma unroll
        for (int c = 0; c < 3; ++c) {
            int id = tid + (c0 + c) * 512;
            int rowIdx = id >> 4;
            int ch = rowIdx / WR, rr = rowIdx - ch * WR;
            const float* src = xb + (size_t)(g * 16 + ch) * HW +
                               (rlo + rr) * WW + c4 * 4;
            sa[c] = *(const float4*)src;
            sb[c] = (c4 == 15) ? sa[c].w : src[4];
        }
    };
    auto stageWrite3 = [&](int c0) {
#pragma unroll
        for (int c = 0; c < 3; ++c) {
            int id = tid + (c0 + c) * 512;
            int rowIdx = id >> 4;
            int ch = rowIdx / WR, rr = rowIdx - ch * WR;
            unsigned* wp = &sWin[ch * CSTR + rr * RSTR + c4 * 4];
            float4 a = sa[c]; float b5 = sb[c];
            wp[0] = (unsigned)f2bf(a.x) | ((unsigned)f2bf(a.y) << 16);
            wp[1] = (unsigned)f2bf(a.y) | ((unsigned)f2bf(a.z) << 16);
            wp[2] = (unsigned)f2bf(a.z) | ((unsigned)f2bf(a.w) << 16);
            wp[3] = (unsigned)f2bf(a.w) | ((unsigned)f2bf(b5) << 16);
        }
    };

    if (fast) {
        stageLoad3(0, 0); stageWrite3(0);
        stageLoad3(0, 3); stageWrite3(3);
        __syncthreads();
        produceAll(0, true);
        __syncthreads();
        for (int g = 0; g < 16; ++g) {
            const bool hn = g < 15;
            if (hn) stageLoad3(g + 1, 0);
            consumeStep(g, 0); consumeStep(g, 1); consumeStep(g, 2);
            consumeStep(g, 3); consumeStep(g, 4);
            if (hn) { stageWrite3(0); stageLoad3(g + 1, 3); }
            consumeStep(g, 5); consumeStep(g, 6); consumeStep(g, 7);
            consumeStep(g, 8); consumeStep(g, 9);
            if (hn) stageWrite3(3);
            __syncthreads();
            if (hn) {
                produceAll(g + 1, true);
                __syncthreads();
            }
        }
    } else {
        for (int g = 0; g < 16; ++g) {
            produceAll(g, false);
            __syncthreads();
#pragma unroll
            for (int ks = 0; ks < 10; ++ks) consumeStep(g, ks);
            __syncthreads();
        }
    }

    // ---- epilogue: f32x4 stores, C layout col=lane&31(=o), row=m(pixel) ----
#pragma unroll
    for (int t = 0; t < 2; ++t) {
        f32x16 A = t ? acc1 : acc0;
        int o = (ntp * 2 + t) * 32 + (l & 31);
        float bb = b_dcn[o];
        float* ob = out + ((size_t)(b * COUT + o) * HH + i) * WW + mtc * 32 + 4 * h;
#pragma unroll
        for (int rq = 0; rq < 4; ++rq) {
            f32x4 v = {A[rq * 4 + 0] + bb, A[rq * 4 + 1] + bb,
                       A[rq * 4 + 2] + bb, A[rq * 4 + 3] + bb};
            *(f32x4*)(ob + rq * 8) = v;
        }
    }
}

extern "C" void kernel_launch(void* const* d_in, const int* in_sizes, int n_in,
                              void* d_out, int out_size, void* d_ws, size_t ws_size,
                              hipStream_t stream) {
    const float* x       = (const float*)d_in[0];
    const float* w_off   = (const float*)d_in[1];
    const float* b_off   = (const float*)d_in[2];
    const float* w_scale = (const float*)d_in[3];
    const float* b_scale = (const float*)d_in[4];
    const float* w_dcn   = (const float*)d_in[5];
    const float* b_dcn   = (const float*)d_in[6];
    float* out = (float*)d_out;
    float* ws  = (float*)d_ws;

    prep_kernel<<<dim3(66),   dim3(256), 0, stream>>>(w_dcn, w_off, w_scale, ws);
    mid_kernel <<<dim3(1152), dim3(256), 0, stream>>>(x, w_dcn, ws);
    dcn_main_kernel<<<dim3(512), dim3(512), 0, stream>>>(
        x, b_off, b_scale, b_dcn, ws, out);
}